// Round 5
// baseline (335.218 us; speedup 1.0000x reference)
//
#include <hip/hip_runtime.h>
#include <stdint.h>

typedef __bf16 bf16x8 __attribute__((ext_vector_type(8)));
typedef float f32x4 __attribute__((ext_vector_type(4)));

__device__ __forceinline__ unsigned short f2bf(float f) {
    union { float f; uint32_t u; } v; v.f = f;
    uint32_t u = v.u;
    return (unsigned short)((u + 0x7FFFu + ((u >> 16) & 1u)) >> 16);
}

__device__ __forceinline__ bf16x8 cvt8(float4 a, float4 b, float s) {
    union { unsigned short u[8]; bf16x8 v; } r;
    r.u[0] = f2bf(a.x * s); r.u[1] = f2bf(a.y * s);
    r.u[2] = f2bf(a.z * s); r.u[3] = f2bf(a.w * s);
    r.u[4] = f2bf(b.x * s); r.u[5] = f2bf(b.y * s);
    r.u[6] = f2bf(b.z * s); r.u[7] = f2bf(b.w * s);
    return r.v;
}

#define VT_STRIDE 72   // vT 32x64 tile, +8 pad
#define PS_STRIDE 72   // p 16x64 per-wave strip, +8 pad
#define XH_STRIDE 40   // xh 16x32 per-wave strip, +8 pad

// ---------------- combined precompute kernel ----------------
// blocks [0,6144):  bm[(w*6+h)*4096 + c*64 + r] = mask[w][r][c] + rpb[rpi[r][c]][h]
// blocks [6144,6288): wf[((kk*12+ct)*64+lane)*8+e] = bf16(W[ct*16+(lane&15)][kk*32+(lane>>4)*8+e])
__global__ void prep_all(const int* __restrict__ rpi32,
                         const float* __restrict__ mask,
                         const float* __restrict__ rpb,
                         const float* __restrict__ proj_w,
                         float* __restrict__ bm,
                         unsigned short* __restrict__ wf) {
    int bid = blockIdx.x;
    int tid = threadIdx.x;
    if (bid < 6144) {
        __shared__ int is64_s;
        if (tid == 0) {
            int s = 0;
            #pragma unroll
            for (int i = 0; i < 16; ++i) s |= rpi32[2 * i + 1];
            is64_s = (s == 0);
        }
        __syncthreads();
        int g = bid * 256 + tid;              // < 64*6*4096
        int wh = g >> 12;                     // w*6+h
        int e  = g & 4095;                    // c*64 + r
        int c = e >> 6, r = e & 63;
        int h = wh % 6, w = wh / 6;
        int rc = r * 64 + c;
        int rv = is64_s ? rpi32[2 * rc] : rpi32[rc];
        bm[g] = mask[w * 4096 + rc] + rpb[rv * 6 + h];
    } else {
        int g = (bid - 6144) * 256 + tid;     // < 36864
        int e = g & 7;
        int lane = (g >> 3) & 63;
        int kkct = g >> 9;
        int kk = kkct / 12, ct = kkct % 12;
        int co = ct * 16 + (lane & 15);
        int ki = kk * 32 + (lane >> 4) * 8 + e;
        wf[g] = f2bf(proj_w[co * 192 + ki]);
    }
}

// ---------------- fast fused kernel: V-only LDS, 6 barriers, per-head proj ----------------

__global__ __launch_bounds__(256, 4)
void winattn_fast(const float* __restrict__ qkv,
                  const float* __restrict__ bm,
                  const unsigned short* __restrict__ wf,
                  const float* __restrict__ proj_b,
                  float* __restrict__ out) {
    __shared__ __align__(16) unsigned short vT_s[2][32 * VT_STRIDE];   // 9216 B dbuf
    __shared__ __align__(16) unsigned short p_s[4 * 16 * PS_STRIDE];   // 9216 B per-wave strips
    __shared__ __align__(16) unsigned short xh_s[4 * 16 * XH_STRIDE];  // 5120 B per-wave strips

    const int tid  = threadIdx.x;
    const int b    = blockIdx.x;
    const int lane = tid & 63;
    const int wv   = tid >> 6;
    const int l16  = lane & 15;
    const int lhi  = lane >> 4;
    const int qbase = wv * 16;
    const float scale = 0.17677669529663687f;

    const float* qkv_b = qkv + (size_t)b * 64 * 576;
    const float* bm_w  = bm + (size_t)(b & 63) * 6 * 4096;

    // V staging geometry: thread covers (tokA, dA) and (tokA+32, dA)
    const int tokA = tid >> 3;
    const int dA   = (tid & 7) << 2;
    const float4* vA = (const float4*)(qkv_b + tokA * 576 + dA + 384);        // [h*8]
    const float4* vB = (const float4*)(qkv_b + (tokA + 32) * 576 + dA + 384); // [h*8]

    float4 v0, v1;

#define LOADV(h_) do { v0 = vA[(h_) * 8]; v1 = vB[(h_) * 8]; } while (0)
#define STOREV(buf) do {                                    \
        (buf)[(dA + 0) * VT_STRIDE + tokA] = f2bf(v0.x);    \
        (buf)[(dA + 1) * VT_STRIDE + tokA] = f2bf(v0.y);    \
        (buf)[(dA + 2) * VT_STRIDE + tokA] = f2bf(v0.z);    \
        (buf)[(dA + 3) * VT_STRIDE + tokA] = f2bf(v0.w);    \
        (buf)[(dA + 0) * VT_STRIDE + tokA + 32] = f2bf(v1.x); \
        (buf)[(dA + 1) * VT_STRIDE + tokA + 32] = f2bf(v1.y); \
        (buf)[(dA + 2) * VT_STRIDE + tokA + 32] = f2bf(v1.z); \
        (buf)[(dA + 3) * VT_STRIDE + tokA + 32] = f2bf(v1.w); } while (0)

    LOADV(0);
    STOREV(vT_s[0]);
    LOADV(1);

    unsigned short* pw = p_s + wv * 16 * PS_STRIDE;
    unsigned short* xh = xh_s + wv * 16 * XH_STRIDE;

    f32x4 oacc[12];
    #pragma unroll
    for (int ct = 0; ct < 12; ++ct) oacc[ct] = (f32x4){0.f, 0.f, 0.f, 0.f};

    for (int h = 0; h < 6; ++h) {
        __syncthreads();                         // vT_s[h&1] (head h) now visible
        if (h < 5) STOREV(vT_s[(h + 1) & 1]);    // regs loaded a full head ago
        if (h < 4) LOADV(h + 2);                 // refill in-flight pair

        // ---------- direct global->frag loads for Q (own rows) and K (all rows) ----------
        const float* qptr = qkv_b + (qbase + l16) * 576 + h * 32 + lhi * 8;
        float4 qf0 = ((const float4*)qptr)[0];
        float4 qf1 = ((const float4*)qptr)[1];
        float4 kf[8];
        #pragma unroll
        for (int nt = 0; nt < 4; ++nt) {
            const float* kptr = qkv_b + 192 + (nt * 16 + l16) * 576 + h * 32 + lhi * 8;
            kf[2 * nt]     = ((const float4*)kptr)[0];
            kf[2 * nt + 1] = ((const float4*)kptr)[1];
        }
        // bias+mask (precombined, transposed): 4x float4, L2/L3-hot
        const float* bmh = bm_w + h * 4096;
        float4 bv[4];
        #pragma unroll
        for (int nt = 0; nt < 4; ++nt)
            bv[nt] = *(const float4*)&bmh[(nt * 16 + l16) * 64 + qbase + lhi * 4];

        bf16x8 aq = cvt8(qf0, qf1, scale);

        // ---------- S = Q K^T ----------
        float lg[4][4];
        #pragma unroll
        for (int nt = 0; nt < 4; ++nt) {
            bf16x8 bk = cvt8(kf[2 * nt], kf[2 * nt + 1], 1.0f);
            f32x4 c = {0.f, 0.f, 0.f, 0.f};
            c = __builtin_amdgcn_mfma_f32_16x16x32_bf16(aq, bk, c, 0, 0, 0);
            lg[nt][0] = c[0] + bv[nt].x; lg[nt][1] = c[1] + bv[nt].y;
            lg[nt][2] = c[2] + bv[nt].z; lg[nt][3] = c[3] + bv[nt].w;
        }

        // ---------- row softmax (division deferred) ----------
        float srow[4];
        #pragma unroll
        for (int j = 0; j < 4; ++j) {
            float m = fmaxf(fmaxf(lg[0][j], lg[1][j]), fmaxf(lg[2][j], lg[3][j]));
            #pragma unroll
            for (int o = 1; o < 16; o <<= 1) m = fmaxf(m, __shfl_xor(m, o, 64));
            float s = 0.f;
            #pragma unroll
            for (int nt = 0; nt < 4; ++nt) { lg[nt][j] = __expf(lg[nt][j] - m); s += lg[nt][j]; }
            #pragma unroll
            for (int o = 1; o < 16; o <<= 1) s += __shfl_xor(s, o, 64);
            srow[j] = s;
        }

        // P -> own-wave strip (same-wave ordering, no barrier)
        #pragma unroll
        for (int nt = 0; nt < 4; ++nt)
            #pragma unroll
            for (int j = 0; j < 4; ++j)
                pw[(lhi * 4 + j) * PS_STRIDE + nt * 16 + l16] = f2bf(lg[nt][j]);

        // ---------- X_h = P V ----------
        const unsigned short* vt = vT_s[h & 1];
        f32x4 xo[2] = {{0.f,0.f,0.f,0.f},{0.f,0.f,0.f,0.f}};
        #pragma unroll
        for (int kk = 0; kk < 2; ++kk) {
            bf16x8 pa = *(const bf16x8*)&pw[l16 * PS_STRIDE + kk * 32 + lhi * 8];
            #pragma unroll
            for (int dt = 0; dt < 2; ++dt) {
                bf16x8 vb = *(const bf16x8*)&vt[(dt * 16 + l16) * VT_STRIDE + kk * 32 + lhi * 8];
                xo[dt] = __builtin_amdgcn_mfma_f32_16x16x32_bf16(pa, vb, xo[dt], 0, 0, 0);
            }
        }
        // X_h (C-layout) -> own-wave strip (A-layout round trip)
        #pragma unroll
        for (int j = 0; j < 4; ++j) {
            float inv = __builtin_amdgcn_rcpf(srow[j]);
            #pragma unroll
            for (int dt = 0; dt < 2; ++dt)
                xh[(lhi * 4 + j) * XH_STRIDE + dt * 16 + l16] = f2bf(xo[dt][j] * inv);
        }

        // ---------- per-head proj accumulation: oacc += X_h @ W[:, h*32:+32]^T ----------
        bf16x8 ax = *(const bf16x8*)&xh[l16 * XH_STRIDE + lhi * 8];
        #pragma unroll
        for (int ct = 0; ct < 12; ++ct) {
            bf16x8 bw = *(const bf16x8*)&wf[((h * 12 + ct) * 64 + lane) * 8];
            oacc[ct] = __builtin_amdgcn_mfma_f32_16x16x32_bf16(ax, bw, oacc[ct], 0, 0, 0);
        }
    }
#undef LOADV
#undef STOREV

    float* outb = out + (size_t)b * 64 * 192;
    #pragma unroll
    for (int ct = 0; ct < 12; ++ct) {
        int co = ct * 16 + l16;
        float bias = proj_b[co];
        #pragma unroll
        for (int j = 0; j < 4; ++j) {
            int n = qbase + lhi * 4 + j;
            outb[n * 192 + co] = oacc[ct][j] + bias;
        }
    }
}

// ---------------- fallback (self-contained, used if ws too small) ----------------

#define QS_STRIDE 40
#define XS_STRIDE 200
#define WS_STRIDE 40

__global__ __launch_bounds__(256)
void winattn_fused(const float* __restrict__ qkv,
                   const int* __restrict__ rpi32,
                   const float* __restrict__ mask,
                   const float* __restrict__ rpb_table,
                   const float* __restrict__ proj_w,
                   const float* __restrict__ proj_b,
                   float* __restrict__ out) {
    __shared__ __align__(16) unsigned short x_s[64 * XS_STRIDE];
    __shared__ __align__(16) unsigned short u_s[12032];
    __shared__ float rpb_s[225];
    __shared__ int rpi_is64_s;

    unsigned short* q_s  = u_s;
    unsigned short* k_s  = u_s + 2560;
    unsigned short* vT_s = u_s + 5120;
    unsigned short* p_s  = u_s + 7424;
    unsigned short* w_s  = u_s;

    const int tid  = threadIdx.x;
    const int b    = blockIdx.x;
    const int lane = tid & 63;
    const int wv   = tid >> 6;
    const int l16  = lane & 15;
    const int lhi  = lane >> 4;
    const int qbase = wv * 16;
    const float scale = 0.17677669529663687f;

    if (tid == 0) {
        int s = 0;
        #pragma unroll
        for (int i = 0; i < 16; ++i) s |= rpi32[2 * i + 1];
        rpi_is64_s = (s == 0) ? 1 : 0;
    }

    const float* maskw = mask + (size_t)(b & 63) * 4096;
    const float* qkv_b = qkv + (size_t)b * 64 * 576;

    for (int h = 0; h < 6; ++h) {
        for (int idx = tid; idx < 64 * 8; idx += 256) {
            int tok = idx >> 3, d = (idx & 7) << 2;
            const float4* base = (const float4*)(qkv_b + tok * 576 + h * 32 + d);
            float4 qv = base[0];
            float4 kv = base[48];
            float4 vv = base[96];
            ushort4 qh, kh;
            qh.x = f2bf(qv.x * scale); qh.y = f2bf(qv.y * scale);
            qh.z = f2bf(qv.z * scale); qh.w = f2bf(qv.w * scale);
            kh.x = f2bf(kv.x); kh.y = f2bf(kv.y); kh.z = f2bf(kv.z); kh.w = f2bf(kv.w);
            *(ushort4*)&q_s[tok * QS_STRIDE + d] = qh;
            *(ushort4*)&k_s[tok * QS_STRIDE + d] = kh;
            vT_s[(d + 0) * VT_STRIDE + tok] = f2bf(vv.x);
            vT_s[(d + 1) * VT_STRIDE + tok] = f2bf(vv.y);
            vT_s[(d + 2) * VT_STRIDE + tok] = f2bf(vv.z);
            vT_s[(d + 3) * VT_STRIDE + tok] = f2bf(vv.w);
        }
        if (tid < 225) rpb_s[tid] = rpb_table[tid * 6 + h];
        __syncthreads();
        const int is64 = rpi_is64_s;

        bf16x8 aq = *(const bf16x8*)&q_s[(qbase + l16) * QS_STRIDE + lhi * 8];
        float lg[4][4];
        #pragma unroll
        for (int nt = 0; nt < 4; ++nt) {
            bf16x8 bk = *(const bf16x8*)&k_s[(nt * 16 + l16) * QS_STRIDE + lhi * 8];
            f32x4 c = {0.f, 0.f, 0.f, 0.f};
            c = __builtin_amdgcn_mfma_f32_16x16x32_bf16(aq, bk, c, 0, 0, 0);
            #pragma unroll
            for (int j = 0; j < 4; ++j) lg[nt][j] = c[j];
        }
        #pragma unroll
        for (int nt = 0; nt < 4; ++nt) {
            int c = nt * 16 + l16;
            #pragma unroll
            for (int j = 0; j < 4; ++j) {
                int r = qbase + lhi * 4 + j;
                int e = r * 64 + c;
                int rv = is64 ? rpi32[2 * e] : rpi32[e];
                lg[nt][j] += rpb_s[rv] + maskw[e];
            }
        }
        float srow[4];
        float p[4][4];
        #pragma unroll
        for (int j = 0; j < 4; ++j) {
            float m = fmaxf(fmaxf(lg[0][j], lg[1][j]), fmaxf(lg[2][j], lg[3][j]));
            #pragma unroll
            for (int o = 1; o < 16; o <<= 1) m = fmaxf(m, __shfl_xor(m, o, 64));
            float s = 0.f;
            #pragma unroll
            for (int nt = 0; nt < 4; ++nt) { p[nt][j] = __expf(lg[nt][j] - m); s += p[nt][j]; }
            #pragma unroll
            for (int o = 1; o < 16; o <<= 1) s += __shfl_xor(s, o, 64);
            srow[j] = s;
        }
        __syncthreads();
        unsigned short* pw = p_s + wv * 16 * PS_STRIDE;
        #pragma unroll
        for (int nt = 0; nt < 4; ++nt)
            #pragma unroll
            for (int j = 0; j < 4; ++j)
                pw[(lhi * 4 + j) * PS_STRIDE + nt * 16 + l16] = f2bf(p[nt][j]);
        __syncthreads();

        f32x4 xo[2] = {{0.f,0.f,0.f,0.f},{0.f,0.f,0.f,0.f}};
        #pragma unroll
        for (int kk = 0; kk < 2; ++kk) {
            bf16x8 pa = *(const bf16x8*)&pw[l16 * PS_STRIDE + kk * 32 + lhi * 8];
            #pragma unroll
            for (int dt = 0; dt < 2; ++dt) {
                bf16x8 vb = *(const bf16x8*)&vT_s[(dt * 16 + l16) * VT_STRIDE + kk * 32 + lhi * 8];
                xo[dt] = __builtin_amdgcn_mfma_f32_16x16x32_bf16(pa, vb, xo[dt], 0, 0, 0);
            }
        }
        #pragma unroll
        for (int j = 0; j < 4; ++j) {
            float inv = 1.f / srow[j];
            int n = qbase + lhi * 4 + j;
            #pragma unroll
            for (int dt = 0; dt < 2; ++dt)
                x_s[n * XS_STRIDE + h * 32 + dt * 16 + l16] = f2bf(xo[dt][j] * inv);
        }
        __syncthreads();
    }

    f32x4 oacc[12];
    #pragma unroll
    for (int ct = 0; ct < 12; ++ct) oacc[ct] = (f32x4){0.f, 0.f, 0.f, 0.f};
    for (int kk = 0; kk < 6; ++kk) {
        for (int idx = tid; idx < 192 * 8; idx += 256) {
            int co = idx >> 3, d = (idx & 7) << 2;
            float4 wvv = *(const float4*)(proj_w + co * 192 + kk * 32 + d);
            ushort4 wh;
            wh.x = f2bf(wvv.x); wh.y = f2bf(wvv.y); wh.z = f2bf(wvv.z); wh.w = f2bf(wvv.w);
            *(ushort4*)&w_s[co * WS_STRIDE + d] = wh;
        }
        __syncthreads();
        bf16x8 ax = *(const bf16x8*)&x_s[(qbase + l16) * XS_STRIDE + kk * 32 + lhi * 8];
        #pragma unroll
        for (int ct = 0; ct < 12; ++ct) {
            bf16x8 bw = *(const bf16x8*)&w_s[(ct * 16 + l16) * WS_STRIDE + lhi * 8];
            oacc[ct] = __builtin_amdgcn_mfma_f32_16x16x32_bf16(ax, bw, oacc[ct], 0, 0, 0);
        }
        __syncthreads();
    }
    float* outb = out + (size_t)b * 64 * 192;
    #pragma unroll
    for (int ct = 0; ct < 12; ++ct) {
        int co = ct * 16 + l16;
        float bias = proj_b[co];
        #pragma unroll
        for (int j = 0; j < 4; ++j) {
            int n = qbase + lhi * 4 + j;
            outb[n * 192 + co] = oacc[ct][j] + bias;
        }
    }
}

extern "C" void kernel_launch(void* const* d_in, const int* in_sizes, int n_in,
                              void* d_out, int out_size, void* d_ws, size_t ws_size,
                              hipStream_t stream) {
    (void)in_sizes; (void)n_in; (void)out_size;
    const float* qkv       = (const float*)d_in[0];
    const int*   rpi       = (const int*)d_in[1];
    const float* mask      = (const float*)d_in[2];
    const float* rpb_table = (const float*)d_in[3];
    const float* proj_w    = (const float*)d_in[4];
    const float* proj_b    = (const float*)d_in[5];
    float* out = (float*)d_out;

    const size_t BM_BYTES = (size_t)64 * 6 * 4096 * sizeof(float);   // 6,291,456
    const size_t WF_BYTES = (size_t)36864 * sizeof(unsigned short);  // 73,728

    if (ws_size >= BM_BYTES + WF_BYTES) {
        float* bmp = (float*)d_ws;
        unsigned short* wfp = (unsigned short*)((char*)d_ws + BM_BYTES);
        prep_all<<<6144 + 144, 256, 0, stream>>>(rpi, mask, rpb_table, proj_w, bmp, wfp);
        winattn_fast<<<4096, 256, 0, stream>>>(qkv, bmp, wfp, proj_b, out);
    } else {
        winattn_fused<<<4096, 256, 0, stream>>>(qkv, rpi, mask, rpb_table, proj_w, proj_b, out);
    }
}

// Round 6
// 274.994 us; speedup vs baseline: 1.2190x; 1.2190x over previous
//
#include <hip/hip_runtime.h>
#include <stdint.h>

typedef __bf16 bf16x8 __attribute__((ext_vector_type(8)));
typedef float f32x4 __attribute__((ext_vector_type(4)));

__device__ __forceinline__ unsigned short f2bf(float f) {
    union { float f; uint32_t u; } v; v.f = f;
    uint32_t u = v.u;
    return (unsigned short)((u + 0x7FFFu + ((u >> 16) & 1u)) >> 16);
}

__device__ __forceinline__ bf16x8 cvt8(float4 a, float4 b, float s) {
    union { unsigned short u[8]; bf16x8 v; } r;
    r.u[0] = f2bf(a.x * s); r.u[1] = f2bf(a.y * s);
    r.u[2] = f2bf(a.z * s); r.u[3] = f2bf(a.w * s);
    r.u[4] = f2bf(b.x * s); r.u[5] = f2bf(b.y * s);
    r.u[6] = f2bf(b.z * s); r.u[7] = f2bf(b.w * s);
    return r.v;
}

#define KS_STRIDE 40   // k 64x32 tile, +8 pad
#define VT_STRIDE 72   // vT 32x64 tile, +8 pad
#define PS_STRIDE 72   // p 16x64 per-wave strip, +8 pad
#define XH_STRIDE 40   // xh 16x32 per-wave strip, +8 pad

// ---------------- combined precompute kernel ----------------
// blocks [0,6144):  bm[(w*6+h)*4096 + c*64 + r] = mask[w][r][c] + rpb[rpi[r][c]][h]
// blocks [6144,6288): wf[((kk*12+ct)*64+lane)*8+e] = bf16(W[ct*16+(lane&15)][kk*32+(lane>>4)*8+e])
__global__ void prep_all(const int* __restrict__ rpi32,
                         const float* __restrict__ mask,
                         const float* __restrict__ rpb,
                         const float* __restrict__ proj_w,
                         float* __restrict__ bm,
                         unsigned short* __restrict__ wf) {
    int bid = blockIdx.x;
    int tid = threadIdx.x;
    if (bid < 6144) {
        __shared__ int is64_s;
        if (tid == 0) {
            int s = 0;
            #pragma unroll
            for (int i = 0; i < 16; ++i) s |= rpi32[2 * i + 1];
            is64_s = (s == 0);
        }
        __syncthreads();
        int g = bid * 256 + tid;              // < 64*6*4096
        int wh = g >> 12;                     // w*6+h
        int e  = g & 4095;                    // c*64 + r
        int c = e >> 6, r = e & 63;
        int h = wh % 6, w = wh / 6;
        int rc = r * 64 + c;
        int rv = is64_s ? rpi32[2 * rc] : rpi32[rc];
        bm[g] = mask[w * 4096 + rc] + rpb[rv * 6 + h];
    } else {
        int g = (bid - 6144) * 256 + tid;     // < 36864
        int e = g & 7;
        int lane = (g >> 3) & 63;
        int kkct = g >> 9;
        int kk = kkct / 12, ct = kkct % 12;
        int co = ct * 16 + (lane & 15);
        int ki = kk * 32 + (lane >> 4) * 8 + e;
        wf[g] = f2bf(proj_w[co * 192 + ki]);
    }
}

// ------- fast fused kernel: K+V dbuf LDS (pipelined), Q in regs (prefetched), 6 barriers -------

__global__ __launch_bounds__(256, 4)
void winattn_fast(const float* __restrict__ qkv,
                  const float* __restrict__ bm,
                  const unsigned short* __restrict__ wf,
                  const float* __restrict__ proj_b,
                  float* __restrict__ out) {
    __shared__ __align__(16) unsigned short k_s[2][64 * KS_STRIDE];    // 10240 B dbuf
    __shared__ __align__(16) unsigned short vT_s[2][32 * VT_STRIDE];   //  9216 B dbuf
    __shared__ __align__(16) unsigned short p_s[4 * 16 * PS_STRIDE];   //  9216 B per-wave strips
    __shared__ __align__(16) unsigned short xh_s[4 * 16 * XH_STRIDE];  //  5120 B per-wave strips

    const int tid  = threadIdx.x;
    const int b    = blockIdx.x;
    const int lane = tid & 63;
    const int wv   = tid >> 6;
    const int l16  = lane & 15;
    const int lhi  = lane >> 4;
    const int qbase = wv * 16;
    const float scale = 0.17677669529663687f;

    const float* qkv_b = qkv + (size_t)b * 64 * 576;
    const float* bm_w  = bm + (size_t)(b & 63) * 6 * 4096;

    // K/V staging geometry (coalesced): thread covers rows tokA and tokA+32, cols dA..dA+3
    const int tokA = tid >> 3;
    const int dA   = (tid & 7) << 2;
    const float* kA = qkv_b + 192 + tokA * 576 + dA;   // + h*32 per head
    const float* kB = kA + 32 * 576;
    const float* vA = qkv_b + 384 + tokA * 576 + dA;
    const float* vB = vA + 32 * 576;

    float4 k0, k1, v0, v1;

#define LOADKV(h_) do { int o = (h_) * 32;                      \
        k0 = *(const float4*)(kA + o); k1 = *(const float4*)(kB + o); \
        v0 = *(const float4*)(vA + o); v1 = *(const float4*)(vB + o); } while (0)

#define STOREKV(bi) do {                                        \
        ushort4 kh;                                             \
        kh.x = f2bf(k0.x); kh.y = f2bf(k0.y);                   \
        kh.z = f2bf(k0.z); kh.w = f2bf(k0.w);                   \
        *(ushort4*)&k_s[bi][tokA * KS_STRIDE + dA] = kh;        \
        kh.x = f2bf(k1.x); kh.y = f2bf(k1.y);                   \
        kh.z = f2bf(k1.z); kh.w = f2bf(k1.w);                   \
        *(ushort4*)&k_s[bi][(tokA + 32) * KS_STRIDE + dA] = kh; \
        vT_s[bi][(dA + 0) * VT_STRIDE + tokA] = f2bf(v0.x);     \
        vT_s[bi][(dA + 1) * VT_STRIDE + tokA] = f2bf(v0.y);     \
        vT_s[bi][(dA + 2) * VT_STRIDE + tokA] = f2bf(v0.z);     \
        vT_s[bi][(dA + 3) * VT_STRIDE + tokA] = f2bf(v0.w);     \
        vT_s[bi][(dA + 0) * VT_STRIDE + tokA + 32] = f2bf(v1.x); \
        vT_s[bi][(dA + 1) * VT_STRIDE + tokA + 32] = f2bf(v1.y); \
        vT_s[bi][(dA + 2) * VT_STRIDE + tokA + 32] = f2bf(v1.z); \
        vT_s[bi][(dA + 3) * VT_STRIDE + tokA + 32] = f2bf(v1.w); } while (0)

    // Q prefetch (per-wave own rows, double-buffered in regs)
    const float* qp = qkv_b + (qbase + l16) * 576 + lhi * 8;   // + h*32 per head
    float4 qfA[2], qfB[2];

    // prologue: stage head 0, prefetch head-1 K/V into regs, prefetch head-0 Q
    LOADKV(0);
    qfA[0] = *(const float4*)(qp);
    qfB[0] = *(const float4*)(qp + 4);
    STOREKV(0);
    LOADKV(1);

    unsigned short* pw = p_s + wv * 16 * PS_STRIDE;
    unsigned short* xh = xh_s + wv * 16 * XH_STRIDE;

    f32x4 oacc[12];
    #pragma unroll
    for (int ct = 0; ct < 12; ++ct) oacc[ct] = (f32x4){0.f, 0.f, 0.f, 0.f};

    #pragma unroll
    for (int h = 0; h < 6; ++h) {
        __syncthreads();                          // stage buffers for head h visible

        // issue next-head global loads immediately (a full head of compute to land)
        if (h < 5) {
            qfA[(h + 1) & 1] = *(const float4*)(qp + (h + 1) * 32);
            qfB[(h + 1) & 1] = *(const float4*)(qp + (h + 1) * 32 + 4);
        }
        // bias+mask loads (L2-hot), issued before compute
        const float* bmh = bm_w + h * 4096;
        float4 bv[4];
        #pragma unroll
        for (int nt = 0; nt < 4; ++nt)
            bv[nt] = *(const float4*)&bmh[(nt * 16 + l16) * 64 + qbase + lhi * 4];

        // ---------- S = Q K^T ----------
        bf16x8 aq = cvt8(qfA[h & 1], qfB[h & 1], scale);
        const unsigned short* ks = k_s[h & 1];
        const unsigned short* vt = vT_s[h & 1];
        float lg[4][4];
        #pragma unroll
        for (int nt = 0; nt < 4; ++nt) {
            bf16x8 bk = *(const bf16x8*)&ks[(nt * 16 + l16) * KS_STRIDE + lhi * 8];
            f32x4 c = {0.f, 0.f, 0.f, 0.f};
            c = __builtin_amdgcn_mfma_f32_16x16x32_bf16(aq, bk, c, 0, 0, 0);
            lg[nt][0] = c[0] + bv[nt].x; lg[nt][1] = c[1] + bv[nt].y;
            lg[nt][2] = c[2] + bv[nt].z; lg[nt][3] = c[3] + bv[nt].w;
        }

        // ---------- row softmax (division deferred) ----------
        float srow[4];
        #pragma unroll
        for (int j = 0; j < 4; ++j) {
            float m = fmaxf(fmaxf(lg[0][j], lg[1][j]), fmaxf(lg[2][j], lg[3][j]));
            #pragma unroll
            for (int o = 1; o < 16; o <<= 1) m = fmaxf(m, __shfl_xor(m, o, 64));
            float s = 0.f;
            #pragma unroll
            for (int nt = 0; nt < 4; ++nt) { lg[nt][j] = __expf(lg[nt][j] - m); s += lg[nt][j]; }
            #pragma unroll
            for (int o = 1; o < 16; o <<= 1) s += __shfl_xor(s, o, 64);
            srow[j] = s;
        }

        // mid-body: write next head's stage (safe: everyone passed top-of-h barrier,
        // buf (h+1)&1 was last READ during head h-1), then refill regs for h+2
        if (h < 5) STOREKV((h + 1) & 1);
        if (h < 4) LOADKV(h + 2);

        // P -> own-wave strip (same-wave ordering, no barrier)
        #pragma unroll
        for (int nt = 0; nt < 4; ++nt)
            #pragma unroll
            for (int j = 0; j < 4; ++j)
                pw[(lhi * 4 + j) * PS_STRIDE + nt * 16 + l16] = f2bf(lg[nt][j]);

        // ---------- X_h = P V ----------
        f32x4 xo[2] = {{0.f,0.f,0.f,0.f},{0.f,0.f,0.f,0.f}};
        #pragma unroll
        for (int kk = 0; kk < 2; ++kk) {
            bf16x8 pa = *(const bf16x8*)&pw[l16 * PS_STRIDE + kk * 32 + lhi * 8];
            #pragma unroll
            for (int dt = 0; dt < 2; ++dt) {
                bf16x8 vb = *(const bf16x8*)&vt[(dt * 16 + l16) * VT_STRIDE + kk * 32 + lhi * 8];
                xo[dt] = __builtin_amdgcn_mfma_f32_16x16x32_bf16(pa, vb, xo[dt], 0, 0, 0);
            }
        }
        // X_h (C-layout) -> own-wave strip (A-layout round trip)
        #pragma unroll
        for (int j = 0; j < 4; ++j) {
            float inv = __builtin_amdgcn_rcpf(srow[j]);
            #pragma unroll
            for (int dt = 0; dt < 2; ++dt)
                xh[(lhi * 4 + j) * XH_STRIDE + dt * 16 + l16] = f2bf(xo[dt][j] * inv);
        }

        // ---------- per-head proj accumulation: oacc += X_h @ W[:, h*32:+32]^T ----------
        bf16x8 ax = *(const bf16x8*)&xh[l16 * XH_STRIDE + lhi * 8];
        #pragma unroll
        for (int ct = 0; ct < 12; ++ct) {
            bf16x8 bw = *(const bf16x8*)&wf[((h * 12 + ct) * 64 + lane) * 8];
            oacc[ct] = __builtin_amdgcn_mfma_f32_16x16x32_bf16(ax, bw, oacc[ct], 0, 0, 0);
        }
    }
#undef LOADKV
#undef STOREKV

    float* outb = out + (size_t)b * 64 * 192;
    #pragma unroll
    for (int ct = 0; ct < 12; ++ct) {
        int co = ct * 16 + l16;
        float bias = proj_b[co];
        #pragma unroll
        for (int j = 0; j < 4; ++j) {
            int n = qbase + lhi * 4 + j;
            outb[n * 192 + co] = oacc[ct][j] + bias;
        }
    }
}

// ---------------- fallback (self-contained, used if ws too small) ----------------

#define QS_STRIDE 40
#define XS_STRIDE 200
#define WS_STRIDE 40

__global__ __launch_bounds__(256)
void winattn_fused(const float* __restrict__ qkv,
                   const int* __restrict__ rpi32,
                   const float* __restrict__ mask,
                   const float* __restrict__ rpb_table,
                   const float* __restrict__ proj_w,
                   const float* __restrict__ proj_b,
                   float* __restrict__ out) {
    __shared__ __align__(16) unsigned short x_s[64 * XS_STRIDE];
    __shared__ __align__(16) unsigned short u_s[12032];
    __shared__ float rpb_s[225];
    __shared__ int rpi_is64_s;

    unsigned short* q_s  = u_s;
    unsigned short* k_s  = u_s + 2560;
    unsigned short* vT_s = u_s + 5120;
    unsigned short* p_s  = u_s + 7424;
    unsigned short* w_s  = u_s;

    const int tid  = threadIdx.x;
    const int b    = blockIdx.x;
    const int lane = tid & 63;
    const int wv   = tid >> 6;
    const int l16  = lane & 15;
    const int lhi  = lane >> 4;
    const int qbase = wv * 16;
    const float scale = 0.17677669529663687f;

    if (tid == 0) {
        int s = 0;
        #pragma unroll
        for (int i = 0; i < 16; ++i) s |= rpi32[2 * i + 1];
        rpi_is64_s = (s == 0) ? 1 : 0;
    }

    const float* maskw = mask + (size_t)(b & 63) * 4096;
    const float* qkv_b = qkv + (size_t)b * 64 * 576;

    for (int h = 0; h < 6; ++h) {
        for (int idx = tid; idx < 64 * 8; idx += 256) {
            int tok = idx >> 3, d = (idx & 7) << 2;
            const float4* base = (const float4*)(qkv_b + tok * 576 + h * 32 + d);
            float4 qv = base[0];
            float4 kv = base[48];
            float4 vv = base[96];
            ushort4 qh, kh;
            qh.x = f2bf(qv.x * scale); qh.y = f2bf(qv.y * scale);
            qh.z = f2bf(qv.z * scale); qh.w = f2bf(qv.w * scale);
            kh.x = f2bf(kv.x); kh.y = f2bf(kv.y); kh.z = f2bf(kv.z); kh.w = f2bf(kv.w);
            *(ushort4*)&q_s[tok * QS_STRIDE + d] = qh;
            *(ushort4*)&k_s[tok * QS_STRIDE + d] = kh;
            vT_s[(d + 0) * VT_STRIDE + tok] = f2bf(vv.x);
            vT_s[(d + 1) * VT_STRIDE + tok] = f2bf(vv.y);
            vT_s[(d + 2) * VT_STRIDE + tok] = f2bf(vv.z);
            vT_s[(d + 3) * VT_STRIDE + tok] = f2bf(vv.w);
        }
        if (tid < 225) rpb_s[tid] = rpb_table[tid * 6 + h];
        __syncthreads();
        const int is64 = rpi_is64_s;

        bf16x8 aq = *(const bf16x8*)&q_s[(qbase + l16) * QS_STRIDE + lhi * 8];
        float lg[4][4];
        #pragma unroll
        for (int nt = 0; nt < 4; ++nt) {
            bf16x8 bk = *(const bf16x8*)&k_s[(nt * 16 + l16) * QS_STRIDE + lhi * 8];
            f32x4 c = {0.f, 0.f, 0.f, 0.f};
            c = __builtin_amdgcn_mfma_f32_16x16x32_bf16(aq, bk, c, 0, 0, 0);
            #pragma unroll
            for (int j = 0; j < 4; ++j) lg[nt][j] = c[j];
        }
        #pragma unroll
        for (int nt = 0; nt < 4; ++nt) {
            int c = nt * 16 + l16;
            #pragma unroll
            for (int j = 0; j < 4; ++j) {
                int r = qbase + lhi * 4 + j;
                int e = r * 64 + c;
                int rv = is64 ? rpi32[2 * e] : rpi32[e];
                lg[nt][j] += rpb_s[rv] + maskw[e];
            }
        }
        float srow[4];
        float p[4][4];
        #pragma unroll
        for (int j = 0; j < 4; ++j) {
            float m = fmaxf(fmaxf(lg[0][j], lg[1][j]), fmaxf(lg[2][j], lg[3][j]));
            #pragma unroll
            for (int o = 1; o < 16; o <<= 1) m = fmaxf(m, __shfl_xor(m, o, 64));
            float s = 0.f;
            #pragma unroll
            for (int nt = 0; nt < 4; ++nt) { p[nt][j] = __expf(lg[nt][j] - m); s += p[nt][j]; }
            #pragma unroll
            for (int o = 1; o < 16; o <<= 1) s += __shfl_xor(s, o, 64);
            srow[j] = s;
        }
        __syncthreads();
        unsigned short* pw = p_s + wv * 16 * PS_STRIDE;
        #pragma unroll
        for (int nt = 0; nt < 4; ++nt)
            #pragma unroll
            for (int j = 0; j < 4; ++j)
                pw[(lhi * 4 + j) * PS_STRIDE + nt * 16 + l16] = f2bf(p[nt][j]);
        __syncthreads();

        f32x4 xo[2] = {{0.f,0.f,0.f,0.f},{0.f,0.f,0.f,0.f}};
        #pragma unroll
        for (int kk = 0; kk < 2; ++kk) {
            bf16x8 pa = *(const bf16x8*)&pw[l16 * PS_STRIDE + kk * 32 + lhi * 8];
            #pragma unroll
            for (int dt = 0; dt < 2; ++dt) {
                bf16x8 vb = *(const bf16x8*)&vT_s[(dt * 16 + l16) * VT_STRIDE + kk * 32 + lhi * 8];
                xo[dt] = __builtin_amdgcn_mfma_f32_16x16x32_bf16(pa, vb, xo[dt], 0, 0, 0);
            }
        }
        #pragma unroll
        for (int j = 0; j < 4; ++j) {
            float inv = 1.f / srow[j];
            int n = qbase + lhi * 4 + j;
            #pragma unroll
            for (int dt = 0; dt < 2; ++dt)
                x_s[n * XS_STRIDE + h * 32 + dt * 16 + l16] = f2bf(xo[dt][j] * inv);
        }
        __syncthreads();
    }

    f32x4 oacc[12];
    #pragma unroll
    for (int ct = 0; ct < 12; ++ct) oacc[ct] = (f32x4){0.f, 0.f, 0.f, 0.f};
    for (int kk = 0; kk < 6; ++kk) {
        for (int idx = tid; idx < 192 * 8; idx += 256) {
            int co = idx >> 3, d = (idx & 7) << 2;
            float4 wvv = *(const float4*)(proj_w + co * 192 + kk * 32 + d);
            ushort4 wh;
            wh.x = f2bf(wvv.x); wh.y = f2bf(wvv.y); wh.z = f2bf(wvv.z); wh.w = f2bf(wvv.w);
            *(ushort4*)&w_s[co * WS_STRIDE + d] = wh;
        }
        __syncthreads();
        bf16x8 ax = *(const bf16x8*)&x_s[(qbase + l16) * XS_STRIDE + kk * 32 + lhi * 8];
        #pragma unroll
        for (int ct = 0; ct < 12; ++ct) {
            bf16x8 bw = *(const bf16x8*)&w_s[(ct * 16 + l16) * WS_STRIDE + lhi * 8];
            oacc[ct] = __builtin_amdgcn_mfma_f32_16x16x32_bf16(ax, bw, oacc[ct], 0, 0, 0);
        }
        __syncthreads();
    }
    float* outb = out + (size_t)b * 64 * 192;
    #pragma unroll
    for (int ct = 0; ct < 12; ++ct) {
        int co = ct * 16 + l16;
        float bias = proj_b[co];
        #pragma unroll
        for (int j = 0; j < 4; ++j) {
            int n = qbase + lhi * 4 + j;
            outb[n * 192 + co] = oacc[ct][j] + bias;
        }
    }
}

extern "C" void kernel_launch(void* const* d_in, const int* in_sizes, int n_in,
                              void* d_out, int out_size, void* d_ws, size_t ws_size,
                              hipStream_t stream) {
    (void)in_sizes; (void)n_in; (void)out_size;
    const float* qkv       = (const float*)d_in[0];
    const int*   rpi       = (const int*)d_in[1];
    const float* mask      = (const float*)d_in[2];
    const float* rpb_table = (const float*)d_in[3];
    const float* proj_w    = (const float*)d_in[4];
    const float* proj_b    = (const float*)d_in[5];
    float* out = (float*)d_out;

    const size_t BM_BYTES = (size_t)64 * 6 * 4096 * sizeof(float);   // 6,291,456
    const size_t WF_BYTES = (size_t)36864 * sizeof(unsigned short);  // 73,728

    if (ws_size >= BM_BYTES + WF_BYTES) {
        float* bmp = (float*)d_ws;
        unsigned short* wfp = (unsigned short*)((char*)d_ws + BM_BYTES);
        prep_all<<<6144 + 144, 256, 0, stream>>>(rpi, mask, rpb_table, proj_w, bmp, wfp);
        winattn_fast<<<4096, 256, 0, stream>>>(qkv, bmp, wfp, proj_b, out);
    } else {
        winattn_fused<<<4096, 256, 0, stream>>>(qkv, rpi, mask, rpb_table, proj_w, proj_b, out);
    }
}

// Round 7
// 212.527 us; speedup vs baseline: 1.5773x; 1.2939x over previous
//
#include <hip/hip_runtime.h>
#include <stdint.h>

typedef __bf16 bf16x8 __attribute__((ext_vector_type(8)));
typedef float f32x4 __attribute__((ext_vector_type(4)));

// Native bf16 conversion (RNE): compiler emits v_cvt_pk_bf16_f32 pairs on gfx950
// (learn_hip m240: scalar casts beat hand-written bit-twiddle/inline-asm).
__device__ __forceinline__ unsigned short f2bf(float f) {
    union { __bf16 h; unsigned short u; } v;
    v.h = (__bf16)f;
    return v.u;
}

#define QS_STRIDE 40   // q/k 64x32 tiles, +8 pad
#define VT_STRIDE 72   // vT 32x64 tile, +8 pad
#define PS_STRIDE 72   // p 16x64 per-wave strip, +8 pad
#define XS_STRIDE 200  // x 64x192 tile, +8 pad

// ---------------- combined precompute kernel ----------------
// blocks [0,6144):  bm[(w*6+h)*4096 + c*64 + r] = mask[w][r][c] + rpb[rpi[r][c]][h]
// blocks [6144,6288): wf[((kk*12+ct)*64+lane)*8+e] = bf16(W[ct*16+(lane&15)][kk*32+(lane>>4)*8+e])
__global__ void prep_all(const int* __restrict__ rpi32,
                         const float* __restrict__ mask,
                         const float* __restrict__ rpb,
                         const float* __restrict__ proj_w,
                         float* __restrict__ bm,
                         unsigned short* __restrict__ wf) {
    int bid = blockIdx.x;
    int tid = threadIdx.x;
    if (bid < 6144) {
        __shared__ int is64_s;
        if (tid == 0) {
            int s = 0;
            #pragma unroll
            for (int i = 0; i < 16; ++i) s |= rpi32[2 * i + 1];
            is64_s = (s == 0);
        }
        __syncthreads();
        int g = bid * 256 + tid;              // < 64*6*4096
        int wh = g >> 12;                     // w*6+h
        int e  = g & 4095;                    // c*64 + r
        int c = e >> 6, r = e & 63;
        int h = wh % 6, w = wh / 6;
        int rc = r * 64 + c;
        int rv = is64_s ? rpi32[2 * rc] : rpi32[rc];
        bm[g] = mask[w * 4096 + rc] + rpb[rv * 6 + h];
    } else {
        int g = (bid - 6144) * 256 + tid;     // < 36864
        int e = g & 7;
        int lane = (g >> 3) & 63;
        int kkct = g >> 9;
        int kk = kkct / 12, ct = kkct % 12;
        int co = ct * 16 + (lane & 15);
        int ki = kk * 32 + (lane >> 4) * 8 + e;
        wf[g] = f2bf(proj_w[co * 192 + ki]);
    }
}

// ---------------- fast fused kernel (R4 structure: pipelined staging, 12 barriers) ----------------

__global__ __launch_bounds__(256, 3)
void winattn_fast(const float* __restrict__ qkv,
                  const float* __restrict__ bm,
                  const unsigned short* __restrict__ wf,
                  const float* __restrict__ proj_b,
                  float* __restrict__ out) {
    __shared__ __align__(16) unsigned short x_s[64 * XS_STRIDE];      // 25600 B
    __shared__ __align__(16) unsigned short u_s[7424];                // 14848 B: q|k|vT
    __shared__ __align__(16) unsigned short p_s[4 * 16 * PS_STRIDE];  // 9216 B (own-wave strips)

    unsigned short* q_s  = u_s;          // [64][40]
    unsigned short* k_s  = u_s + 2560;   // [64][40]
    unsigned short* vT_s = u_s + 5120;   // [32][72]

    const int tid  = threadIdx.x;
    const int b    = blockIdx.x;
    const int lane = tid & 63;
    const int wv   = tid >> 6;
    const int l16  = lane & 15;
    const int lhi  = lane >> 4;
    const int qbase = wv * 16;
    const float scale = 0.17677669529663687f;

    const float* qkv_b = qkv + (size_t)b * 64 * 576;
    const float* bm_w  = bm + (size_t)(b & 63) * 6 * 4096;

    // staging geometry: thread covers (tokA, dA) and (tokB = tokA+32, dA)
    const int tokA = tid >> 3;
    const int dA   = (tid & 7) << 2;
    const float4* gA = (const float4*)(qkv_b + tokA * 576 + dA); // head h: +h*8 (f4), k:+48, v:+96
    const float4* gB = (const float4*)(qkv_b + (tokA + 32) * 576 + dA);

    float4 q0, k0, v0, q1, k1, v1;

#define LOADH(h_)  do { int o = (h_) * 8;                         \
        q0 = gA[o];      k0 = gA[o + 48]; v0 = gA[o + 96];        \
        q1 = gB[o];      k1 = gB[o + 48]; v1 = gB[o + 96]; } while (0)

#define STOREH() do {                                             \
        ushort4 qh, kh;                                           \
        qh.x = f2bf(q0.x * scale); qh.y = f2bf(q0.y * scale);     \
        qh.z = f2bf(q0.z * scale); qh.w = f2bf(q0.w * scale);     \
        kh.x = f2bf(k0.x); kh.y = f2bf(k0.y);                     \
        kh.z = f2bf(k0.z); kh.w = f2bf(k0.w);                     \
        *(ushort4*)&q_s[tokA * QS_STRIDE + dA] = qh;              \
        *(ushort4*)&k_s[tokA * QS_STRIDE + dA] = kh;              \
        vT_s[(dA + 0) * VT_STRIDE + tokA] = f2bf(v0.x);           \
        vT_s[(dA + 1) * VT_STRIDE + tokA] = f2bf(v0.y);           \
        vT_s[(dA + 2) * VT_STRIDE + tokA] = f2bf(v0.z);           \
        vT_s[(dA + 3) * VT_STRIDE + tokA] = f2bf(v0.w);           \
        qh.x = f2bf(q1.x * scale); qh.y = f2bf(q1.y * scale);     \
        qh.z = f2bf(q1.z * scale); qh.w = f2bf(q1.w * scale);     \
        kh.x = f2bf(k1.x); kh.y = f2bf(k1.y);                     \
        kh.z = f2bf(k1.z); kh.w = f2bf(k1.w);                     \
        *(ushort4*)&q_s[(tokA + 32) * QS_STRIDE + dA] = qh;       \
        *(ushort4*)&k_s[(tokA + 32) * QS_STRIDE + dA] = kh;       \
        vT_s[(dA + 0) * VT_STRIDE + tokA + 32] = f2bf(v1.x);      \
        vT_s[(dA + 1) * VT_STRIDE + tokA + 32] = f2bf(v1.y);      \
        vT_s[(dA + 2) * VT_STRIDE + tokA + 32] = f2bf(v1.z);      \
        vT_s[(dA + 3) * VT_STRIDE + tokA + 32] = f2bf(v1.w); } while (0)

    LOADH(0);
    STOREH();

    unsigned short* pw = p_s + wv * 16 * PS_STRIDE;

    for (int h = 0; h < 6; ++h) {
        __syncthreads();                 // A: stage for head h visible
        if (h < 5) LOADH(h + 1);         // issue next head's loads early (latency hides under compute)

        // bm loads issued up front too
        const float* bmh = bm_w + h * 4096;
        float4 bv[4];
        #pragma unroll
        for (int nt = 0; nt < 4; ++nt)
            bv[nt] = *(const float4*)&bmh[(nt * 16 + l16) * 64 + qbase + lhi * 4];

        // ---------- S = Q K^T ----------
        bf16x8 aq = *(const bf16x8*)&q_s[(qbase + l16) * QS_STRIDE + lhi * 8];
        float lg[4][4];
        #pragma unroll
        for (int nt = 0; nt < 4; ++nt) {
            bf16x8 bk = *(const bf16x8*)&k_s[(nt * 16 + l16) * QS_STRIDE + lhi * 8];
            f32x4 c = {0.f, 0.f, 0.f, 0.f};
            c = __builtin_amdgcn_mfma_f32_16x16x32_bf16(aq, bk, c, 0, 0, 0);
            lg[nt][0] = c[0] + bv[nt].x; lg[nt][1] = c[1] + bv[nt].y;
            lg[nt][2] = c[2] + bv[nt].z; lg[nt][3] = c[3] + bv[nt].w;
        }

        // ---------- row softmax (division deferred) ----------
        float srow[4];
        float p[4][4];
        #pragma unroll
        for (int j = 0; j < 4; ++j) {
            float m = fmaxf(fmaxf(lg[0][j], lg[1][j]), fmaxf(lg[2][j], lg[3][j]));
            #pragma unroll
            for (int o = 1; o < 16; o <<= 1) m = fmaxf(m, __shfl_xor(m, o, 64));
            float s = 0.f;
            #pragma unroll
            for (int nt = 0; nt < 4; ++nt) { p[nt][j] = __expf(lg[nt][j] - m); s += p[nt][j]; }
            #pragma unroll
            for (int o = 1; o < 16; o <<= 1) s += __shfl_xor(s, o, 64);
            srow[j] = s;
        }

        // P -> own-wave LDS strip (same-wave ordering: no barrier needed)
        #pragma unroll
        for (int nt = 0; nt < 4; ++nt)
            #pragma unroll
            for (int j = 0; j < 4; ++j)
                pw[(lhi * 4 + j) * PS_STRIDE + nt * 16 + l16] = f2bf(p[nt][j]);

        // ---------- X_h = P V ----------
        f32x4 xo[2] = {{0.f,0.f,0.f,0.f},{0.f,0.f,0.f,0.f}};
        #pragma unroll
        for (int kk = 0; kk < 2; ++kk) {
            bf16x8 pa = *(const bf16x8*)&pw[l16 * PS_STRIDE + kk * 32 + lhi * 8];
            #pragma unroll
            for (int dt = 0; dt < 2; ++dt) {
                bf16x8 vb = *(const bf16x8*)&vT_s[(dt * 16 + l16) * VT_STRIDE + kk * 32 + lhi * 8];
                xo[dt] = __builtin_amdgcn_mfma_f32_16x16x32_bf16(pa, vb, xo[dt], 0, 0, 0);
            }
        }
        #pragma unroll
        for (int j = 0; j < 4; ++j) {
            float inv = __builtin_amdgcn_rcpf(srow[j]);
            int n = qbase + lhi * 4 + j;
            #pragma unroll
            for (int dt = 0; dt < 2; ++dt)
                x_s[n * XS_STRIDE + h * 32 + dt * 16 + l16] = f2bf(xo[dt][j] * inv);
        }

        __syncthreads();                 // B: all waves done reading q/k/vT
        if (h < 5) STOREH();             // write next head's stage (vmcnt waits land here)
    }
#undef LOADH
#undef STOREH

    // ---------- out = X @ W^T + bias (x_s own-strip reads: no barrier) ----------
    f32x4 oacc[12];
    #pragma unroll
    for (int ct = 0; ct < 12; ++ct) oacc[ct] = (f32x4){0.f, 0.f, 0.f, 0.f};
    #pragma unroll
    for (int kk = 0; kk < 6; ++kk) {
        bf16x8 ax = *(const bf16x8*)&x_s[(qbase + l16) * XS_STRIDE + kk * 32 + lhi * 8];
        #pragma unroll
        for (int ct = 0; ct < 12; ++ct) {
            bf16x8 bw = *(const bf16x8*)&wf[((kk * 12 + ct) * 64 + lane) * 8];
            oacc[ct] = __builtin_amdgcn_mfma_f32_16x16x32_bf16(ax, bw, oacc[ct], 0, 0, 0);
        }
    }
    float* outb = out + (size_t)b * 64 * 192;
    #pragma unroll
    for (int ct = 0; ct < 12; ++ct) {
        int co = ct * 16 + l16;
        float bias = proj_b[co];
        #pragma unroll
        for (int j = 0; j < 4; ++j) {
            int n = qbase + lhi * 4 + j;
            outb[n * 192 + co] = oacc[ct][j] + bias;
        }
    }
}

// ---------------- fallback (self-contained, used if ws too small) ----------------

#define WS_STRIDE 40

__global__ __launch_bounds__(256)
void winattn_fused(const float* __restrict__ qkv,
                   const int* __restrict__ rpi32,
                   const float* __restrict__ mask,
                   const float* __restrict__ rpb_table,
                   const float* __restrict__ proj_w,
                   const float* __restrict__ proj_b,
                   float* __restrict__ out) {
    __shared__ __align__(16) unsigned short x_s[64 * XS_STRIDE];
    __shared__ __align__(16) unsigned short u_s[12032];
    __shared__ float rpb_s[225];
    __shared__ int rpi_is64_s;

    unsigned short* q_s  = u_s;
    unsigned short* k_s  = u_s + 2560;
    unsigned short* vT_s = u_s + 5120;
    unsigned short* p_s  = u_s + 7424;
    unsigned short* w_s  = u_s;

    const int tid  = threadIdx.x;
    const int b    = blockIdx.x;
    const int lane = tid & 63;
    const int wv   = tid >> 6;
    const int l16  = lane & 15;
    const int lhi  = lane >> 4;
    const int qbase = wv * 16;
    const float scale = 0.17677669529663687f;

    if (tid == 0) {
        int s = 0;
        #pragma unroll
        for (int i = 0; i < 16; ++i) s |= rpi32[2 * i + 1];
        rpi_is64_s = (s == 0) ? 1 : 0;
    }

    const float* maskw = mask + (size_t)(b & 63) * 4096;
    const float* qkv_b = qkv + (size_t)b * 64 * 576;

    for (int h = 0; h < 6; ++h) {
        for (int idx = tid; idx < 64 * 8; idx += 256) {
            int tok = idx >> 3, d = (idx & 7) << 2;
            const float4* base = (const float4*)(qkv_b + tok * 576 + h * 32 + d);
            float4 qv = base[0];
            float4 kv = base[48];
            float4 vv = base[96];
            ushort4 qh, kh;
            qh.x = f2bf(qv.x * scale); qh.y = f2bf(qv.y * scale);
            qh.z = f2bf(qv.z * scale); qh.w = f2bf(qv.w * scale);
            kh.x = f2bf(kv.x); kh.y = f2bf(kv.y); kh.z = f2bf(kv.z); kh.w = f2bf(kv.w);
            *(ushort4*)&q_s[tok * QS_STRIDE + d] = qh;
            *(ushort4*)&k_s[tok * QS_STRIDE + d] = kh;
            vT_s[(d + 0) * VT_STRIDE + tok] = f2bf(vv.x);
            vT_s[(d + 1) * VT_STRIDE + tok] = f2bf(vv.y);
            vT_s[(d + 2) * VT_STRIDE + tok] = f2bf(vv.z);
            vT_s[(d + 3) * VT_STRIDE + tok] = f2bf(vv.w);
        }
        if (tid < 225) rpb_s[tid] = rpb_table[tid * 6 + h];
        __syncthreads();
        const int is64 = rpi_is64_s;

        bf16x8 aq = *(const bf16x8*)&q_s[(qbase + l16) * QS_STRIDE + lhi * 8];
        float lg[4][4];
        #pragma unroll
        for (int nt = 0; nt < 4; ++nt) {
            bf16x8 bk = *(const bf16x8*)&k_s[(nt * 16 + l16) * QS_STRIDE + lhi * 8];
            f32x4 c = {0.f, 0.f, 0.f, 0.f};
            c = __builtin_amdgcn_mfma_f32_16x16x32_bf16(aq, bk, c, 0, 0, 0);
            #pragma unroll
            for (int j = 0; j < 4; ++j) lg[nt][j] = c[j];
        }
        #pragma unroll
        for (int nt = 0; nt < 4; ++nt) {
            int c = nt * 16 + l16;
            #pragma unroll
            for (int j = 0; j < 4; ++j) {
                int r = qbase + lhi * 4 + j;
                int e = r * 64 + c;
                int rv = is64 ? rpi32[2 * e] : rpi32[e];
                lg[nt][j] += rpb_s[rv] + maskw[e];
            }
        }
        float srow[4];
        float p[4][4];
        #pragma unroll
        for (int j = 0; j < 4; ++j) {
            float m = fmaxf(fmaxf(lg[0][j], lg[1][j]), fmaxf(lg[2][j], lg[3][j]));
            #pragma unroll
            for (int o = 1; o < 16; o <<= 1) m = fmaxf(m, __shfl_xor(m, o, 64));
            float s = 0.f;
            #pragma unroll
            for (int nt = 0; nt < 4; ++nt) { p[nt][j] = __expf(lg[nt][j] - m); s += p[nt][j]; }
            #pragma unroll
            for (int o = 1; o < 16; o <<= 1) s += __shfl_xor(s, o, 64);
            srow[j] = s;
        }
        __syncthreads();
        unsigned short* pw = p_s + wv * 16 * PS_STRIDE;
        #pragma unroll
        for (int nt = 0; nt < 4; ++nt)
            #pragma unroll
            for (int j = 0; j < 4; ++j)
                pw[(lhi * 4 + j) * PS_STRIDE + nt * 16 + l16] = f2bf(p[nt][j]);
        __syncthreads();

        f32x4 xo[2] = {{0.f,0.f,0.f,0.f},{0.f,0.f,0.f,0.f}};
        #pragma unroll
        for (int kk = 0; kk < 2; ++kk) {
            bf16x8 pa = *(const bf16x8*)&pw[l16 * PS_STRIDE + kk * 32 + lhi * 8];
            #pragma unroll
            for (int dt = 0; dt < 2; ++dt) {
                bf16x8 vb = *(const bf16x8*)&vT_s[(dt * 16 + l16) * VT_STRIDE + kk * 32 + lhi * 8];
                xo[dt] = __builtin_amdgcn_mfma_f32_16x16x32_bf16(pa, vb, xo[dt], 0, 0, 0);
            }
        }
        #pragma unroll
        for (int j = 0; j < 4; ++j) {
            float inv = 1.f / srow[j];
            int n = qbase + lhi * 4 + j;
            #pragma unroll
            for (int dt = 0; dt < 2; ++dt)
                x_s[n * XS_STRIDE + h * 32 + dt * 16 + l16] = f2bf(xo[dt][j] * inv);
        }
        __syncthreads();
    }

    f32x4 oacc[12];
    #pragma unroll
    for (int ct = 0; ct < 12; ++ct) oacc[ct] = (f32x4){0.f, 0.f, 0.f, 0.f};
    for (int kk = 0; kk < 6; ++kk) {
        for (int idx = tid; idx < 192 * 8; idx += 256) {
            int co = idx >> 3, d = (idx & 7) << 2;
            float4 wvv = *(const float4*)(proj_w + co * 192 + kk * 32 + d);
            ushort4 wh;
            wh.x = f2bf(wvv.x); wh.y = f2bf(wvv.y); wh.z = f2bf(wvv.z); wh.w = f2bf(wvv.w);
            *(ushort4*)&w_s[co * WS_STRIDE + d] = wh;
        }
        __syncthreads();
        bf16x8 ax = *(const bf16x8*)&x_s[(qbase + l16) * XS_STRIDE + kk * 32 + lhi * 8];
        #pragma unroll
        for (int ct = 0; ct < 12; ++ct) {
            bf16x8 bw = *(const bf16x8*)&w_s[(ct * 16 + l16) * WS_STRIDE + lhi * 8];
            oacc[ct] = __builtin_amdgcn_mfma_f32_16x16x32_bf16(ax, bw, oacc[ct], 0, 0, 0);
        }
        __syncthreads();
    }
    float* outb = out + (size_t)b * 64 * 192;
    #pragma unroll
    for (int ct = 0; ct < 12; ++ct) {
        int co = ct * 16 + l16;
        float bias = proj_b[co];
        #pragma unroll
        for (int j = 0; j < 4; ++j) {
            int n = qbase + lhi * 4 + j;
            outb[n * 192 + co] = oacc[ct][j] + bias;
        }
    }
}

extern "C" void kernel_launch(void* const* d_in, const int* in_sizes, int n_in,
                              void* d_out, int out_size, void* d_ws, size_t ws_size,
                              hipStream_t stream) {
    (void)in_sizes; (void)n_in; (void)out_size;
    const float* qkv       = (const float*)d_in[0];
    const int*   rpi       = (const int*)d_in[1];
    const float* mask      = (const float*)d_in[2];
    const float* rpb_table = (const float*)d_in[3];
    const float* proj_w    = (const float*)d_in[4];
    const float* proj_b    = (const float*)d_in[5];
    float* out = (float*)d_out;

    const size_t BM_BYTES = (size_t)64 * 6 * 4096 * sizeof(float);   // 6,291,456
    const size_t WF_BYTES = (size_t)36864 * sizeof(unsigned short);  // 73,728

    if (ws_size >= BM_BYTES + WF_BYTES) {
        float* bmp = (float*)d_ws;
        unsigned short* wfp = (unsigned short*)((char*)d_ws + BM_BYTES);
        prep_all<<<6144 + 144, 256, 0, stream>>>(rpi, mask, rpb_table, proj_w, bmp, wfp);
        winattn_fast<<<4096, 256, 0, stream>>>(qkv, bmp, wfp, proj_b, out);
    } else {
        winattn_fused<<<4096, 256, 0, stream>>>(qkv, rpi, mask, rpb_table, proj_w, proj_b, out);
    }
}

// Round 8
// 192.900 us; speedup vs baseline: 1.7378x; 1.1017x over previous
//
#include <hip/hip_runtime.h>
#include <stdint.h>

typedef __bf16 bf16x8 __attribute__((ext_vector_type(8)));
typedef float f32x4 __attribute__((ext_vector_type(4)));

// Native bf16 conversion (RNE): compiler emits v_cvt_pk_bf16_f32 on gfx950.
__device__ __forceinline__ unsigned short f2bf(float f) {
    union { __bf16 h; unsigned short u; } v;
    v.h = (__bf16)f;
    return v.u;
}

#define QS_STRIDE 40   // q/k 64x32 tiles, +8 pad
#define VT_STRIDE 72   // vT 32x64 tile, +8 pad
#define PS_STRIDE 72   // p 16x64 per-wave strip, +8 pad
#define XS_STRIDE 200  // x 64x192 tile, +8 pad

// ---------------- combined precompute kernel ----------------
// blocks [0,6144):  bm[(w*6+h)*4096 + r*64 + c] = mask[w][r][c] + rpb[rpi[r][c]][h]
//                   (identity layout: r=query row, c=key col; coalesced mask read)
// blocks [6144,6288): wf[((kk*12+ct)*64+lane)*8+e] = bf16(W[ct*16+(lane&15)][kk*32+(lane>>4)*8+e])
__global__ void prep_all(const int* __restrict__ rpi32,
                         const float* __restrict__ mask,
                         const float* __restrict__ rpb,
                         const float* __restrict__ proj_w,
                         float* __restrict__ bm,
                         unsigned short* __restrict__ wf) {
    int bid = blockIdx.x;
    int tid = threadIdx.x;
    if (bid < 6144) {
        __shared__ int is64_s;
        if (tid == 0) {
            int s = 0;
            #pragma unroll
            for (int i = 0; i < 16; ++i) s |= rpi32[2 * i + 1];
            is64_s = (s == 0);
        }
        __syncthreads();
        int g = bid * 256 + tid;              // < 64*6*4096
        int wh = g >> 12;                     // w*6+h
        int e  = g & 4095;                    // r*64 + c
        int h = wh % 6, w = wh / 6;
        int rv = is64_s ? rpi32[2 * e] : rpi32[e];
        bm[g] = mask[w * 4096 + e] + rpb[rv * 6 + h];
    } else {
        int g = (bid - 6144) * 256 + tid;     // < 36864
        int e = g & 7;
        int lane = (g >> 3) & 63;
        int kkct = g >> 9;
        int kk = kkct / 12, ct = kkct % 12;
        int co = ct * 16 + (lane & 15);
        int ki = kk * 32 + (lane >> 4) * 8 + e;
        wf[g] = f2bf(proj_w[co * 192 + ki]);
    }
}

// ------ fast fused kernel (R4 pipeline + swapped-QK^T lane-local softmax) ------

__global__ __launch_bounds__(256, 3)
void winattn_fast(const float* __restrict__ qkv,
                  const float* __restrict__ bm,
                  const unsigned short* __restrict__ wf,
                  const float* __restrict__ proj_b,
                  float* __restrict__ out) {
    __shared__ __align__(16) unsigned short x_s[64 * XS_STRIDE];      // 25600 B
    __shared__ __align__(16) unsigned short u_s[7424];                // 14848 B: q|k|vT
    __shared__ __align__(16) unsigned short p_s[4 * 16 * PS_STRIDE];  // 9216 B (own-wave strips)

    unsigned short* q_s  = u_s;          // [64][40]
    unsigned short* k_s  = u_s + 2560;   // [64][40]
    unsigned short* vT_s = u_s + 5120;   // [32][72]

    const int tid  = threadIdx.x;
    const int b    = blockIdx.x;
    const int lane = tid & 63;
    const int wv   = tid >> 6;
    const int l16  = lane & 15;
    const int lhi  = lane >> 4;
    const int qbase = wv * 16;
    const float scale = 0.17677669529663687f;

    const float* qkv_b = qkv + (size_t)b * 64 * 576;
    const float* bm_w  = bm + (size_t)(b & 63) * 6 * 4096;

    // staging geometry: thread covers (tokA, dA) and (tokB = tokA+32, dA)
    const int tokA = tid >> 3;
    const int dA   = (tid & 7) << 2;
    const float4* gA = (const float4*)(qkv_b + tokA * 576 + dA); // head h: +h*8 (f4), k:+48, v:+96
    const float4* gB = (const float4*)(qkv_b + (tokA + 32) * 576 + dA);

    float4 q0, k0, v0, q1, k1, v1;

#define LOADH(h_)  do { int o = (h_) * 8;                         \
        q0 = gA[o];      k0 = gA[o + 48]; v0 = gA[o + 96];        \
        q1 = gB[o];      k1 = gB[o + 48]; v1 = gB[o + 96]; } while (0)

#define STOREH() do {                                             \
        ushort4 qh, kh;                                           \
        qh.x = f2bf(q0.x * scale); qh.y = f2bf(q0.y * scale);     \
        qh.z = f2bf(q0.z * scale); qh.w = f2bf(q0.w * scale);     \
        kh.x = f2bf(k0.x); kh.y = f2bf(k0.y);                     \
        kh.z = f2bf(k0.z); kh.w = f2bf(k0.w);                     \
        *(ushort4*)&q_s[tokA * QS_STRIDE + dA] = qh;              \
        *(ushort4*)&k_s[tokA * QS_STRIDE + dA] = kh;              \
        vT_s[(dA + 0) * VT_STRIDE + tokA] = f2bf(v0.x);           \
        vT_s[(dA + 1) * VT_STRIDE + tokA] = f2bf(v0.y);           \
        vT_s[(dA + 2) * VT_STRIDE + tokA] = f2bf(v0.z);           \
        vT_s[(dA + 3) * VT_STRIDE + tokA] = f2bf(v0.w);           \
        qh.x = f2bf(q1.x * scale); qh.y = f2bf(q1.y * scale);     \
        qh.z = f2bf(q1.z * scale); qh.w = f2bf(q1.w * scale);     \
        kh.x = f2bf(k1.x); kh.y = f2bf(k1.y);                     \
        kh.z = f2bf(k1.z); kh.w = f2bf(k1.w);                     \
        *(ushort4*)&q_s[(tokA + 32) * QS_STRIDE + dA] = qh;       \
        *(ushort4*)&k_s[(tokA + 32) * QS_STRIDE + dA] = kh;       \
        vT_s[(dA + 0) * VT_STRIDE + tokA + 32] = f2bf(v1.x);      \
        vT_s[(dA + 1) * VT_STRIDE + tokA + 32] = f2bf(v1.y);      \
        vT_s[(dA + 2) * VT_STRIDE + tokA + 32] = f2bf(v1.z);      \
        vT_s[(dA + 3) * VT_STRIDE + tokA + 32] = f2bf(v1.w); } while (0)

    LOADH(0);
    STOREH();

    unsigned short* pw = p_s + wv * 16 * PS_STRIDE;

    for (int h = 0; h < 6; ++h) {
        __syncthreads();                 // A: stage for head h visible
        if (h < 5) LOADH(h + 1);         // issue next head's loads early

        // bias+mask for this wave's 16 q-rows: lane needs bias[q=qbase+l16][k=nt*16+lhi*4+j]
        const float* bmh = bm_w + h * 4096;
        float4 bv[4];
        #pragma unroll
        for (int nt = 0; nt < 4; ++nt)
            bv[nt] = *(const float4*)&bmh[(qbase + l16) * 64 + nt * 16 + lhi * 4];

        // ---------- S^T = K Q^T (swapped: lane l16 holds q-column qbase+l16) ----------
        bf16x8 aq = *(const bf16x8*)&q_s[(qbase + l16) * QS_STRIDE + lhi * 8];
        float lg[4][4];   // lg[nt][j]: S[q=qbase+l16][k=nt*16+lhi*4+j] + bias
        #pragma unroll
        for (int nt = 0; nt < 4; ++nt) {
            bf16x8 bk = *(const bf16x8*)&k_s[(nt * 16 + l16) * QS_STRIDE + lhi * 8];
            f32x4 c = {0.f, 0.f, 0.f, 0.f};
            c = __builtin_amdgcn_mfma_f32_16x16x32_bf16(bk, aq, c, 0, 0, 0); // swapped operands
            lg[nt][0] = c[0] + bv[nt].x; lg[nt][1] = c[1] + bv[nt].y;
            lg[nt][2] = c[2] + bv[nt].z; lg[nt][3] = c[3] + bv[nt].w;
        }

        // ---------- lane-local softmax: 16 local values + 2-lane-hop reduce ----------
        float m = lg[0][0];
        #pragma unroll
        for (int nt = 0; nt < 4; ++nt)
            #pragma unroll
            for (int j = 0; j < 4; ++j) m = fmaxf(m, lg[nt][j]);
        m = fmaxf(m, __shfl_xor(m, 16, 64));
        m = fmaxf(m, __shfl_xor(m, 32, 64));
        float s = 0.f;
        #pragma unroll
        for (int nt = 0; nt < 4; ++nt)
            #pragma unroll
            for (int j = 0; j < 4; ++j) { lg[nt][j] = __expf(lg[nt][j] - m); s += lg[nt][j]; }
        s += __shfl_xor(s, 16, 64);
        s += __shfl_xor(s, 32, 64);
        float inv = __builtin_amdgcn_rcpf(s);

        // P (pre-normalized) -> own-wave strip: 4x packed ushort4, row q=l16
        #pragma unroll
        for (int nt = 0; nt < 4; ++nt) {
            ushort4 ph;
            ph.x = f2bf(lg[nt][0] * inv); ph.y = f2bf(lg[nt][1] * inv);
            ph.z = f2bf(lg[nt][2] * inv); ph.w = f2bf(lg[nt][3] * inv);
            *(ushort4*)&pw[l16 * PS_STRIDE + nt * 16 + lhi * 4] = ph;
        }

        // ---------- X_h = P V ----------
        f32x4 xo[2] = {{0.f,0.f,0.f,0.f},{0.f,0.f,0.f,0.f}};
        #pragma unroll
        for (int kk = 0; kk < 2; ++kk) {
            bf16x8 pa = *(const bf16x8*)&pw[l16 * PS_STRIDE + kk * 32 + lhi * 8];
            #pragma unroll
            for (int dt = 0; dt < 2; ++dt) {
                bf16x8 vb = *(const bf16x8*)&vT_s[(dt * 16 + l16) * VT_STRIDE + kk * 32 + lhi * 8];
                xo[dt] = __builtin_amdgcn_mfma_f32_16x16x32_bf16(pa, vb, xo[dt], 0, 0, 0);
            }
        }
        // X_h (C-layout: row q=qbase+lhi*4+j, col d=dt*16+l16), already normalized
        #pragma unroll
        for (int j = 0; j < 4; ++j) {
            int n = qbase + lhi * 4 + j;
            #pragma unroll
            for (int dt = 0; dt < 2; ++dt)
                x_s[n * XS_STRIDE + h * 32 + dt * 16 + l16] = f2bf(xo[dt][j]);
        }

        __syncthreads();                 // B: all waves done reading q/k/vT
        if (h < 5) STOREH();             // write next head's stage
    }
#undef LOADH
#undef STOREH

    // ---------- out = X @ W^T + bias (x_s own-strip reads: no barrier) ----------
    f32x4 oacc[12];
    #pragma unroll
    for (int ct = 0; ct < 12; ++ct) oacc[ct] = (f32x4){0.f, 0.f, 0.f, 0.f};
    #pragma unroll
    for (int kk = 0; kk < 6; ++kk) {
        bf16x8 ax = *(const bf16x8*)&x_s[(qbase + l16) * XS_STRIDE + kk * 32 + lhi * 8];
        #pragma unroll
        for (int ct = 0; ct < 12; ++ct) {
            bf16x8 bw = *(const bf16x8*)&wf[((kk * 12 + ct) * 64 + lane) * 8];
            oacc[ct] = __builtin_amdgcn_mfma_f32_16x16x32_bf16(ax, bw, oacc[ct], 0, 0, 0);
        }
    }
    float* outb = out + (size_t)b * 64 * 192;
    #pragma unroll
    for (int ct = 0; ct < 12; ++ct) {
        int co = ct * 16 + l16;
        float bias = proj_b[co];
        #pragma unroll
        for (int j = 0; j < 4; ++j) {
            int n = qbase + lhi * 4 + j;
            outb[n * 192 + co] = oacc[ct][j] + bias;
        }
    }
}

// ---------------- fallback (self-contained, used if ws too small) ----------------

#define WS_STRIDE 40

__global__ __launch_bounds__(256)
void winattn_fused(const float* __restrict__ qkv,
                   const int* __restrict__ rpi32,
                   const float* __restrict__ mask,
                   const float* __restrict__ rpb_table,
                   const float* __restrict__ proj_w,
                   const float* __restrict__ proj_b,
                   float* __restrict__ out) {
    __shared__ __align__(16) unsigned short x_s[64 * XS_STRIDE];
    __shared__ __align__(16) unsigned short u_s[12032];
    __shared__ float rpb_s[225];
    __shared__ int rpi_is64_s;

    unsigned short* q_s  = u_s;
    unsigned short* k_s  = u_s + 2560;
    unsigned short* vT_s = u_s + 5120;
    unsigned short* p_s  = u_s + 7424;
    unsigned short* w_s  = u_s;

    const int tid  = threadIdx.x;
    const int b    = blockIdx.x;
    const int lane = tid & 63;
    const int wv   = tid >> 6;
    const int l16  = lane & 15;
    const int lhi  = lane >> 4;
    const int qbase = wv * 16;
    const float scale = 0.17677669529663687f;

    if (tid == 0) {
        int s = 0;
        #pragma unroll
        for (int i = 0; i < 16; ++i) s |= rpi32[2 * i + 1];
        rpi_is64_s = (s == 0) ? 1 : 0;
    }

    const float* maskw = mask + (size_t)(b & 63) * 4096;
    const float* qkv_b = qkv + (size_t)b * 64 * 576;

    for (int h = 0; h < 6; ++h) {
        for (int idx = tid; idx < 64 * 8; idx += 256) {
            int tok = idx >> 3, d = (idx & 7) << 2;
            const float4* base = (const float4*)(qkv_b + tok * 576 + h * 32 + d);
            float4 qv = base[0];
            float4 kv = base[48];
            float4 vv = base[96];
            ushort4 qh, kh;
            qh.x = f2bf(qv.x * scale); qh.y = f2bf(qv.y * scale);
            qh.z = f2bf(qv.z * scale); qh.w = f2bf(qv.w * scale);
            kh.x = f2bf(kv.x); kh.y = f2bf(kv.y); kh.z = f2bf(kv.z); kh.w = f2bf(kv.w);
            *(ushort4*)&q_s[tok * QS_STRIDE + d] = qh;
            *(ushort4*)&k_s[tok * QS_STRIDE + d] = kh;
            vT_s[(d + 0) * VT_STRIDE + tok] = f2bf(vv.x);
            vT_s[(d + 1) * VT_STRIDE + tok] = f2bf(vv.y);
            vT_s[(d + 2) * VT_STRIDE + tok] = f2bf(vv.z);
            vT_s[(d + 3) * VT_STRIDE + tok] = f2bf(vv.w);
        }
        if (tid < 225) rpb_s[tid] = rpb_table[tid * 6 + h];
        __syncthreads();
        const int is64 = rpi_is64_s;

        bf16x8 aq = *(const bf16x8*)&q_s[(qbase + l16) * QS_STRIDE + lhi * 8];
        float lg[4][4];
        #pragma unroll
        for (int nt = 0; nt < 4; ++nt) {
            bf16x8 bk = *(const bf16x8*)&k_s[(nt * 16 + l16) * QS_STRIDE + lhi * 8];
            f32x4 c = {0.f, 0.f, 0.f, 0.f};
            c = __builtin_amdgcn_mfma_f32_16x16x32_bf16(aq, bk, c, 0, 0, 0);
            #pragma unroll
            for (int j = 0; j < 4; ++j) lg[nt][j] = c[j];
        }
        #pragma unroll
        for (int nt = 0; nt < 4; ++nt) {
            int c = nt * 16 + l16;
            #pragma unroll
            for (int j = 0; j < 4; ++j) {
                int r = qbase + lhi * 4 + j;
                int e = r * 64 + c;
                int rv = is64 ? rpi32[2 * e] : rpi32[e];
                lg[nt][j] += rpb_s[rv] + maskw[e];
            }
        }
        float srow[4];
        float p[4][4];
        #pragma unroll
        for (int j = 0; j < 4; ++j) {
            float m = fmaxf(fmaxf(lg[0][j], lg[1][j]), fmaxf(lg[2][j], lg[3][j]));
            #pragma unroll
            for (int o = 1; o < 16; o <<= 1) m = fmaxf(m, __shfl_xor(m, o, 64));
            float s = 0.f;
            #pragma unroll
            for (int nt = 0; nt < 4; ++nt) { p[nt][j] = __expf(lg[nt][j] - m); s += p[nt][j]; }
            #pragma unroll
            for (int o = 1; o < 16; o <<= 1) s += __shfl_xor(s, o, 64);
            srow[j] = s;
        }
        __syncthreads();
        unsigned short* pw = p_s + wv * 16 * PS_STRIDE;
        #pragma unroll
        for (int nt = 0; nt < 4; ++nt)
            #pragma unroll
            for (int j = 0; j < 4; ++j)
                pw[(lhi * 4 + j) * PS_STRIDE + nt * 16 + l16] = f2bf(p[nt][j]);
        __syncthreads();

        f32x4 xo[2] = {{0.f,0.f,0.f,0.f},{0.f,0.f,0.f,0.f}};
        #pragma unroll
        for (int kk = 0; kk < 2; ++kk) {
            bf16x8 pa = *(const bf16x8*)&pw[l16 * PS_STRIDE + kk * 32 + lhi * 8];
            #pragma unroll
            for (int dt = 0; dt < 2; ++dt) {
                bf16x8 vb = *(const bf16x8*)&vT_s[(dt * 16 + l16) * VT_STRIDE + kk * 32 + lhi * 8];
                xo[dt] = __builtin_amdgcn_mfma_f32_16x16x32_bf16(pa, vb, xo[dt], 0, 0, 0);
            }
        }
        #pragma unroll
        for (int j = 0; j < 4; ++j) {
            float inv = 1.f / srow[j];
            int n = qbase + lhi * 4 + j;
            #pragma unroll
            for (int dt = 0; dt < 2; ++dt)
                x_s[n * XS_STRIDE + h * 32 + dt * 16 + l16] = f2bf(xo[dt][j] * inv);
        }
        __syncthreads();
    }

    f32x4 oacc[12];
    #pragma unroll
    for (int ct = 0; ct < 12; ++ct) oacc[ct] = (f32x4){0.f, 0.f, 0.f, 0.f};
    for (int kk = 0; kk < 6; ++kk) {
        for (int idx = tid; idx < 192 * 8; idx += 256) {
            int co = idx >> 3, d = (idx & 7) << 2;
            float4 wvv = *(const float4*)(proj_w + co * 192 + kk * 32 + d);
            ushort4 wh;
            wh.x = f2bf(wvv.x); wh.y = f2bf(wvv.y); wh.z = f2bf(wvv.z); wh.w = f2bf(wvv.w);
            *(ushort4*)&w_s[co * WS_STRIDE + d] = wh;
        }
        __syncthreads();
        bf16x8 ax = *(const bf16x8*)&x_s[(qbase + l16) * XS_STRIDE + kk * 32 + lhi * 8];
        #pragma unroll
        for (int ct = 0; ct < 12; ++ct) {
            bf16x8 bw = *(const bf16x8*)&w_s[(ct * 16 + l16) * WS_STRIDE + lhi * 8];
            oacc[ct] = __builtin_amdgcn_mfma_f32_16x16x32_bf16(ax, bw, oacc[ct], 0, 0, 0);
        }
        __syncthreads();
    }
    float* outb = out + (size_t)b * 64 * 192;
    #pragma unroll
    for (int ct = 0; ct < 12; ++ct) {
        int co = ct * 16 + l16;
        float bias = proj_b[co];
        #pragma unroll
        for (int j = 0; j < 4; ++j) {
            int n = qbase + lhi * 4 + j;
            outb[n * 192 + co] = oacc[ct][j] + bias;
        }
    }
}

extern "C" void kernel_launch(void* const* d_in, const int* in_sizes, int n_in,
                              void* d_out, int out_size, void* d_ws, size_t ws_size,
                              hipStream_t stream) {
    (void)in_sizes; (void)n_in; (void)out_size;
    const float* qkv       = (const float*)d_in[0];
    const int*   rpi       = (const int*)d_in[1];
    const float* mask      = (const float*)d_in[2];
    const float* rpb_table = (const float*)d_in[3];
    const float* proj_w    = (const float*)d_in[4];
    const float* proj_b    = (const float*)d_in[5];
    float* out = (float*)d_out;

    const size_t BM_BYTES = (size_t)64 * 6 * 4096 * sizeof(float);   // 6,291,456
    const size_t WF_BYTES = (size_t)36864 * sizeof(unsigned short);  // 73,728

    if (ws_size >= BM_BYTES + WF_BYTES) {
        float* bmp = (float*)d_ws;
        unsigned short* wfp = (unsigned short*)((char*)d_ws + BM_BYTES);
        prep_all<<<6144 + 144, 256, 0, stream>>>(rpi, mask, rpb_table, proj_w, bmp, wfp);
        winattn_fast<<<4096, 256, 0, stream>>>(qkv, bmp, wfp, proj_b, out);
    } else {
        winattn_fused<<<4096, 256, 0, stream>>>(qkv, rpi, mask, rpb_table, proj_w, proj_b, out);
    }
}